// Round 3
// baseline (179.941 us; speedup 1.0000x reference)
//
#include <hip/hip_runtime.h>
#include <stdint.h>

typedef __bf16 bf16x8 __attribute__((ext_vector_type(8)));
typedef float  f32x4  __attribute__((ext_vector_type(4)));

#define ATTN_SCALE 2.7621359e-3f   // 1/(sqrt(128)*sqrt(1024))

__device__ __forceinline__ unsigned short f2bf(float f) {
  union { float f; uint32_t u; } v; v.f = f;
  uint32_t u = v.u;
  uint32_t r = (u + 0x7FFFu + ((u >> 16) & 1u)) >> 16;   // RNE
  return (unsigned short)r;
}

__device__ __forceinline__ void load_lds16(const unsigned short* g, unsigned short* l) {
  __builtin_amdgcn_global_load_lds(
      (const __attribute__((address_space(1))) void*)g,
      (__attribute__((address_space(3))) void*)l, 16, 0, 0);
}

__device__ __forceinline__ f32x4 mfma16(bf16x8 a, bf16x8 b, f32x4 c) {
  return __builtin_amdgcn_mfma_f32_16x16x32_bf16(a, b, c, 0, 0, 0);
}

__device__ __forceinline__ bf16x8 ones_bf16() {
  union { unsigned short u[8]; bf16x8 v; } c;
#pragma unroll
  for (int j = 0; j < 8; ++j) c.u[j] = 0x3F80;   // bf16 1.0
  return c.v;
}

// ---------------------------------------------------------------- convert 3 weights
__global__ __launch_bounds__(256) void k_cvtw(const float* __restrict__ a,
                                              const float* __restrict__ b,
                                              const float* __restrict__ c,
                                              unsigned short* __restrict__ dst) {
  int i = blockIdx.x * 256 + threadIdx.x;      // 0..98303 float4 groups
  int sel = i >> 15, off = i & 32767;
  const float* s = (sel == 0) ? a : (sel == 1) ? b : c;
  float4 f = ((const float4*)s)[off];
  ushort4 o;
  o.x = f2bf(f.x); o.y = f2bf(f.y); o.z = f2bf(f.z); o.w = f2bf(f.w);
  ((ushort4*)dst)[i] = o;
}

// ---------------------------------------------------------------- QKV projection GEMM
// Reads X directly as f32 (no separate cvt pass); A reg-staged with the proven
// f2bf RNE bit-twiddle -> ds_write_b128 (bit-identical to a pre-pass). B via
// global_load_lds from pre-converted wbf. 64x128 tiles, grid (256,3) = 768
// blocks = exactly 3 blocks/CU.
__global__ __launch_bounds__(256, 3) void k_proj(
    const float* __restrict__ X,             // [16384][1024] f32
    const unsigned short* __restrict__ W,    // [3][128][1024] bf16
    unsigned short* __restrict__ Qb,         // [16384][128]
    unsigned short* __restrict__ Kb,         // [16384][128]
    unsigned short* __restrict__ Vt)         // [4][128][4096]
{
  __shared__ __align__(16) unsigned short sm[2048 + 4096];   // As[64][32] | Bs[128][32], 12 KB
  unsigned short* As = sm;
  unsigned short* Bs = sm + 2048;
  const int t = threadIdx.x;
  const int mtile = blockIdx.x;          // 0..255 (64 rows each)
  const int nt = blockIdx.y;             // 0..2  (Q, K, V weight)
  const int w = t >> 6, lane = t & 63, quad = lane >> 4, l15 = lane & 15;
  const int wm = w & 1, wn = w >> 1;

  const float* ag0 = X + (size_t)(mtile * 64 + (t >> 2)) * 1024 + (t & 3) * 8;
  const unsigned short* bg0 = W + (size_t)nt * 131072 + (size_t)(t >> 2) * 1024 + (t & 3) * 8;
  unsigned short* aw = &As[(t >> 2) * 32 + (t & 3) * 8];   // == As + t*8 (linear in t)
  unsigned short* bw = &Bs[(t >> 2) * 32 + (t & 3) * 8];   // == Bs + t*8 (linear in t)

  f32x4 acc[2][4] = {};

  for (int kt = 0; kt < 32; ++kt) {
    // issue f32 A loads before the barrier (reg-staged; no LDS hazard)
    float4 a0 = *(const float4*)(ag0 + kt * 32);
    float4 a1 = *(const float4*)(ag0 + kt * 32 + 4);
    __syncthreads();                       // prior MFMA LDS reads done
    load_lds16(bg0 + kt * 32,             bw);
    load_lds16(bg0 + kt * 32 + 64 * 1024, bw + 2048);
    union { unsigned short u[8]; uint4 v; } pa;
    pa.u[0] = f2bf(a0.x); pa.u[1] = f2bf(a0.y);
    pa.u[2] = f2bf(a0.z); pa.u[3] = f2bf(a0.w);
    pa.u[4] = f2bf(a1.x); pa.u[5] = f2bf(a1.y);
    pa.u[6] = f2bf(a1.z); pa.u[7] = f2bf(a1.w);
    *(uint4*)aw = pa.v;                    // ds_write_b128
    __syncthreads();                       // drains A ds_write + B global_load_lds

    bf16x8 af[2], bfr[4];
#pragma unroll
    for (int i = 0; i < 2; ++i)
      af[i] = *(const bf16x8*)&As[(wm * 32 + i * 16 + l15) * 32 + quad * 8];
#pragma unroll
    for (int j = 0; j < 4; ++j)
      bfr[j] = *(const bf16x8*)&Bs[(wn * 64 + j * 16 + l15) * 32 + quad * 8];
#pragma unroll
    for (int i = 0; i < 2; ++i)
#pragma unroll
      for (int j = 0; j < 4; ++j)
        acc[i][j] = mfma16(af[i], bfr[j], acc[i][j]);
  }

  if (nt != 2) {
    const int m0 = mtile * 64 + wm * 32;
#pragma unroll
    for (int i = 0; i < 2; ++i)
#pragma unroll
      for (int j = 0; j < 4; ++j)
#pragma unroll
        for (int r = 0; r < 4; ++r) {
          int m = m0 + i * 16 + quad * 4 + r;
          int n = wn * 64 + j * 16 + l15;
          float v = acc[i][j][r];
          if (nt == 0) Qb[(size_t)m * 128 + n] = f2bf(v * ATTN_SCALE);
          else         Kb[(size_t)m * 128 + n] = f2bf(v);
        }
  } else {
    // transpose through LDS -> coalesced Vt writes
    // NOTE: jj loop MUST be fully unrolled (j indexes the acc register array;
    // runtime index demotes acc to scratch -> massive spill traffic).
    float* Ts = (float*)sm;                   // [64 m][17] f32 (4352 B)
    const int bb = mtile >> 6;
    const int s0 = (mtile & 63) * 64;
#pragma unroll
    for (int jj = 0; jj < 8; ++jj) {
      __syncthreads();
      if (wn == (jj >> 2)) {
        const int j = jj & 3;
#pragma unroll
        for (int i = 0; i < 2; ++i)
#pragma unroll
          for (int r = 0; r < 4; ++r)
            Ts[(wm * 32 + i * 16 + quad * 4 + r) * 17 + l15] = acc[i][j][r];
      }
      __syncthreads();
      int n2 = jj * 16 + (t >> 4);            // d index within this 16-col chunk
      int m2 = (t & 15) * 4;                  // 4 seq rows per thread
      union { unsigned short u[4]; uint2 v; } pk;
#pragma unroll
      for (int e = 0; e < 4; ++e) pk.u[e] = f2bf(Ts[(m2 + e) * 17 + (t >> 4)]);
      *(uint2*)&Vt[((size_t)(bb * 128 + n2)) * 4096 + s0 + m2] = pk.v;
    }
  }
}

// ---------------------------------------------------------------- flash attention
// v3: 1-D grid of 512 with XCD-affine decode (bid%8 = XCD round-robin): each
// XCD serves exactly one (batch, key-half) -> K/V working set ~1 MB < 4 MB
// per-XCD L2, so the per-iter 64 KB/CU K+V stream is L2-hit instead of L3.
// K AND V double-buffered; raw s_barrier with counted vmcnt(4) (never a full
// vmcnt(0) drain in the loop - T3/T4):
//   alpha: vmcnt(4)+bar  certifies K[cur] (V[cur] stays in flight)
//   issue K[i+1] | QK | softmax
//   beta:  vmcnt(4)+lgkm(0)+bar  certifies V[cur] + own P
//   issue V[i+1] | PV
// Buffer disjointness: K[nxt]/V[nxt] writes never overlap live reads (V[nxt]
// readers all passed alpha(i) before the issue point); P is wave-private.
// Numerics identical to the passing kernel (__expf + f2bf pack).
// LDS 75776 B -> 2 blocks/CU.
__global__ __launch_bounds__(256, 2) void k_flash(
    const unsigned short* __restrict__ Qb,   // [4][4096][128] bf16, pre-scaled
    const unsigned short* __restrict__ Kb,   // [4][4096][128] bf16
    const unsigned short* __restrict__ Vt,   // [4][128][4096] bf16
    float* __restrict__ Om,                  // [2][16384][128] f32 partials
    float* __restrict__ lp)                  // [2][16384] row sums
{
  __shared__ __align__(16) unsigned short smem[37888];   // 75776 B
  // K0 [0,8192) K1 [8192,16384) | V0 [16384,24576) V1 [24576,32768) | P [32768,37888)
  unsigned short* Psh = smem + 32768;    // per-wave [32 q][stride 40]
  float* Ob  = (float*)smem;             // epilogue overlay [64][128] f32 (over K bufs)
  float* lsh = (float*)(smem + 32768);   // epilogue overlay [64] f32 (over P)

  const int t = threadIdx.x;
  const int w = t >> 6, lane = t & 63, quad = lane >> 4, l15 = lane & 15;
  const int h = w & 1, p = w >> 1;
  // XCD-affine decode: xcd = bid & 7 (round-robin); pair (2b, 2b+1) = batch b;
  // even XCD of the pair handles keys 0..2047 (sp=0), odd keys 2048..4095.
  const int bid = blockIdx.x;            // 0..511
  const int b   = (bid & 7) >> 1;
  const int sp  = bid & 1;
  const int qt  = bid >> 3;              // 0..63

  const unsigned short* Qg = Qb + (size_t)(b * 4096 + qt * 64 + h * 32) * 128;
  const unsigned short* Kg = Kb + (size_t)b * 4096 * 128;
  const unsigned short* Vg = Vt + (size_t)b * 128 * 4096;

  bf16x8 qf[2][4];
#pragma unroll
  for (int mt = 0; mt < 2; ++mt)
#pragma unroll
    for (int kk = 0; kk < 4; ++kk)
      qf[mt][kk] = *(const bf16x8*)&Qg[(size_t)(mt * 16 + l15) * 128 + kk * 32 + quad * 8];

  f32x4 O[2][8] = {};
  f32x4 Ol[2] = {};

  // staging maps (chunk-XOR swizzled on the fetch side):
  // K rows are read as row = 2*l15+ntk, so swizzle granularity is (row>>1)&7.
  const unsigned short* kg0 = Kg + (size_t)(t >> 4) * 128 + (((t & 15) ^ ((t >> 5) & 7)) * 8);
  const unsigned short* vg0 = Vg + (size_t)(t >> 3) * 4096 + (((t & 7) ^ ((t >> 3) & 7)) * 8);

  const int kt0 = sp * 32;

  // prologue: K(0) -> K0, then V(0) -> V0 (order matters for the vmcnt counts:
  // at alpha(0), vmcnt(4) retires Q-frag loads + K(0), leaves V(0) in flight)
  {
    const unsigned short* kg = kg0 + (size_t)kt0 * 8192;
    unsigned short* kw = &smem[w * 512];
#pragma unroll
    for (int it = 0; it < 4; ++it)
      load_lds16(kg + it * 2048, kw + it * 2048);
    const unsigned short* vg = vg0 + (size_t)kt0 * 64;
    unsigned short* vw = &smem[16384 + w * 512];
#pragma unroll
    for (int it = 0; it < 4; ++it)
      load_lds16(vg + (size_t)it * 131072, vw + it * 2048);
  }

  for (int i = 0; i < 32; ++i) {
    const int cur = i & 1, nxt = cur ^ 1;
    const int ktn = (i < 31) ? (kt0 + i + 1) : kt0;   // wrap dummy on last iter
                                                      // (keeps vmcnt counts constant;
                                                      // drained by the epilogue
                                                      // __syncthreads before overlay)

    // alpha: own K[cur] (oldest 4 outstanding) retired, then barrier ->
    // everyone's K[cur] resident. V[cur] (newest 4) stays in flight.
    asm volatile("s_waitcnt vmcnt(4)" ::: "memory");
    asm volatile("s_barrier" ::: "memory");

    // issue K[i+1] -> K[nxt]  (K[nxt]=K[i-1]: all QK(i-1) readers passed beta(i-1))
    {
      const unsigned short* kg = kg0 + (size_t)ktn * 8192;
      unsigned short* kw = &smem[nxt * 8192 + w * 512];
#pragma unroll
      for (int it = 0; it < 4; ++it)
        load_lds16(kg + it * 2048, kw + it * 2048);
    }

    // S = Q K^T on K[cur] (keys paired even/odd: lane l15 holds
    // keys p*32 + 2*l15 + ntk)
    const unsigned short* Kshc = &smem[cur * 8192];
    f32x4 sc[2][2] = {};
#pragma unroll
    for (int ntk = 0; ntk < 2; ++ntk) {
      const int row = p * 32 + 2 * l15 + ntk;
#pragma unroll
      for (int kk = 0; kk < 4; ++kk) {
        bf16x8 kf = *(const bf16x8*)&Kshc[row * 128 + (((kk * 4 + quad) ^ (l15 & 7)) * 8)];
        sc[0][ntk] = mfma16(qf[0][kk], kf, sc[0][ntk]);
        sc[1][ntk] = mfma16(qf[1][kk], kf, sc[1][ntk]);
      }
    }

    // P = exp(S) (no max shift), packed pair writes (keys 2*l15, 2*l15+1)
#pragma unroll
    for (int mt = 0; mt < 2; ++mt)
#pragma unroll
      for (int r = 0; r < 4; ++r) {
        float e0 = __expf(sc[mt][0][r]);
        float e1 = __expf(sc[mt][1][r]);
        int row = mt * 16 + quad * 4 + r;
        uint32_t pk = (uint32_t)f2bf(e0) | ((uint32_t)f2bf(e1) << 16);
        *(uint32_t*)&Psh[w * 1280 + row * 40 + 2 * l15] = pk;
      }

    // beta: own V[cur] (oldest remaining 4) retired + own P written, then
    // barrier -> everyone's V[cur] resident. K[i+1] stays in flight.
    asm volatile("s_waitcnt vmcnt(4) lgkmcnt(0)" ::: "memory");
    asm volatile("s_barrier" ::: "memory");

    // issue V[i+1] -> V[nxt]  (V[nxt]=V[i-1]: all PV(i-1) readers passed alpha(i))
    {
      const unsigned short* vg = vg0 + (size_t)ktn * 64;
      unsigned short* vw = &smem[16384 + nxt * 8192 + w * 512];
#pragma unroll
      for (int it = 0; it < 4; ++it)
        load_lds16(vg + (size_t)it * 131072, vw + it * 2048);
    }

    bf16x8 pf0 = *(const bf16x8*)&Psh[w * 1280 + l15 * 40 + quad * 8];
    bf16x8 pf1 = *(const bf16x8*)&Psh[w * 1280 + (16 + l15) * 40 + quad * 8];
    const bf16x8 one = ones_bf16();
    Ol[0] = mfma16(pf0, one, Ol[0]);     // row-sums of P (free l accumulate)
    Ol[1] = mfma16(pf1, one, Ol[1]);
    const unsigned short* Vshc = &smem[16384 + cur * 8192];
#pragma unroll
    for (int dt = 0; dt < 8; ++dt) {
      bf16x8 vf = *(const bf16x8*)&Vshc[(dt * 16 + l15) * 64 + (((p * 4 + quad) ^ (l15 & 7)) * 8)];
      O[0][dt] = mfma16(pf0, vf, O[0][dt]);
      O[1][dt] = mfma16(pf1, vf, O[1][dt]);
    }
  }

  // ---- merge the two key-half partials (additive: no max state) ----
  // __syncthreads drains vmcnt(0) (the wrap-around dummy prefetches land in
  // K[nxt]/V[nxt] BEFORE the overlay writes below) + lgkmcnt, then barrier.
  __syncthreads();
  if (p == 1) {
#pragma unroll
    for (int mt = 0; mt < 2; ++mt)
#pragma unroll
      for (int r = 0; r < 4; ++r) {
        int row = h * 32 + mt * 16 + quad * 4 + r;
        if (l15 == 0) lsh[row] = Ol[mt][r];
#pragma unroll
        for (int dt = 0; dt < 8; ++dt)
          Ob[row * 128 + dt * 16 + l15] = O[mt][dt][r];
      }
  }
  __syncthreads();
  if (p == 0) {
    const size_t rowbase = (size_t)b * 4096 + qt * 64;
    float* Omp = Om + (size_t)sp * 2097152;
#pragma unroll
    for (int mt = 0; mt < 2; ++mt)
#pragma unroll
      for (int r = 0; r < 4; ++r) {
        int row = h * 32 + mt * 16 + quad * 4 + r;
#pragma unroll
        for (int dt = 0; dt < 8; ++dt)
          Omp[(rowbase + row) * 128 + dt * 16 + l15] =
              O[mt][dt][r] + Ob[row * 128 + dt * 16 + l15];
        if (l15 == 0)
          lp[(size_t)sp * 16384 + rowbase + row] = Ol[mt][r] + lsh[row];
      }
  }
}

// ---------------------------------------------------------------- merge key-splits
__global__ __launch_bounds__(256) void k_merge(const float* __restrict__ Om,
                                               const float* __restrict__ lp,
                                               float* __restrict__ out) {
  int i = blockIdx.x * 256 + threadIdx.x;   // float4 index, 524288 total
  int row = i >> 5;
  float inv = 1.0f / (lp[row] + lp[16384 + row]);
  float4 a = ((const float4*)Om)[i];
  float4 c = ((const float4*)Om)[524288 + i];
  float4 o;
  o.x = (a.x + c.x) * inv;
  o.y = (a.y + c.y) * inv;
  o.z = (a.z + c.z) * inv;
  o.w = (a.w + c.w) * inv;
  ((float4*)out)[i] = o;
}

// ---------------------------------------------------------------- launch
extern "C" void kernel_launch(void* const* d_in, const int* in_sizes, int n_in,
                              void* d_out, int out_size, void* d_ws, size_t ws_size,
                              hipStream_t stream) {
  const float* x  = (const float*)d_in[0];   // [4,4096,1024]
  const float* Wq = (const float*)d_in[1];   // [128,1024]
  const float* Wk = (const float*)d_in[2];
  const float* Wv = (const float*)d_in[3];
  float* out = (float*)d_out;                // [4,4096,128]

  unsigned short* ws  = (unsigned short*)d_ws;
  unsigned short* wbf = ws;                   // 393,216 ush
  unsigned short* Qb  = wbf + 393216;         // 2,097,152
  unsigned short* Kb  = Qb + 2097152;
  unsigned short* Vt  = Kb + 2097152;         // 2,097,152
  float* Om = (float*)(Vt + 2097152);         // 2*16384*128 f32
  float* lp = Om + 4194304;                   // 2*16384 f32

  k_cvtw<<<384, 256, 0, stream>>>(Wq, Wk, Wv, wbf);
  k_proj<<<dim3(256, 3), 256, 0, stream>>>(x, wbf, Qb, Kb, Vt);
  k_flash<<<512, 256, 0, stream>>>(Qb, Kb, Vt, Om, lp);
  k_merge<<<2048, 256, 0, stream>>>(Om, lp, out);
}

// Round 4
// 178.536 us; speedup vs baseline: 1.0079x; 1.0079x over previous
//
#include <hip/hip_runtime.h>
#include <stdint.h>

typedef __bf16 bf16x8 __attribute__((ext_vector_type(8)));
typedef float  f32x4  __attribute__((ext_vector_type(4)));

#define ATTN_SCALE 2.7621359e-3f   // 1/(sqrt(128)*sqrt(1024))

__device__ __forceinline__ unsigned short f2bf(float f) {
  union { float f; uint32_t u; } v; v.f = f;
  uint32_t u = v.u;
  uint32_t r = (u + 0x7FFFu + ((u >> 16) & 1u)) >> 16;   // RNE
  return (unsigned short)r;
}

__device__ __forceinline__ void load_lds16(const unsigned short* g, unsigned short* l) {
  __builtin_amdgcn_global_load_lds(
      (const __attribute__((address_space(1))) void*)g,
      (__attribute__((address_space(3))) void*)l, 16, 0, 0);
}

__device__ __forceinline__ f32x4 mfma16(bf16x8 a, bf16x8 b, f32x4 c) {
  return __builtin_amdgcn_mfma_f32_16x16x32_bf16(a, b, c, 0, 0, 0);
}

__device__ __forceinline__ bf16x8 ones_bf16() {
  union { unsigned short u[8]; bf16x8 v; } c;
#pragma unroll
  for (int j = 0; j < 8; ++j) c.u[j] = 0x3F80;   // bf16 1.0
  return c.v;
}

// ---------------------------------------------------------------- convert 3 weights
__global__ __launch_bounds__(256) void k_cvtw(const float* __restrict__ a,
                                              const float* __restrict__ b,
                                              const float* __restrict__ c,
                                              unsigned short* __restrict__ dst) {
  int i = blockIdx.x * 256 + threadIdx.x;      // 0..98303 float4 groups
  int sel = i >> 15, off = i & 32767;
  const float* s = (sel == 0) ? a : (sel == 1) ? b : c;
  float4 f = ((const float4*)s)[off];
  ushort4 o;
  o.x = f2bf(f.x); o.y = f2bf(f.y); o.z = f2bf(f.z); o.w = f2bf(f.w);
  ((ushort4*)dst)[i] = o;
}

// ---------------------------------------------------------------- QKV projection GEMM
// [frozen since round 2 - passed twice] Reads X directly as f32; A reg-staged
// with the proven f2bf RNE bit-twiddle -> ds_write_b128. B via global_load_lds
// from pre-converted wbf. 64x128 tiles, grid (256,3) = 768 blocks = 3/CU.
__global__ __launch_bounds__(256, 3) void k_proj(
    const float* __restrict__ X,             // [16384][1024] f32
    const unsigned short* __restrict__ W,    // [3][128][1024] bf16
    unsigned short* __restrict__ Qb,         // [16384][128]
    unsigned short* __restrict__ Kb,         // [16384][128]
    unsigned short* __restrict__ Vt)         // [4][128][4096]
{
  __shared__ __align__(16) unsigned short sm[2048 + 4096];   // As[64][32] | Bs[128][32], 12 KB
  unsigned short* As = sm;
  unsigned short* Bs = sm + 2048;
  const int t = threadIdx.x;
  const int mtile = blockIdx.x;          // 0..255 (64 rows each)
  const int nt = blockIdx.y;             // 0..2  (Q, K, V weight)
  const int w = t >> 6, lane = t & 63, quad = lane >> 4, l15 = lane & 15;
  const int wm = w & 1, wn = w >> 1;

  const float* ag0 = X + (size_t)(mtile * 64 + (t >> 2)) * 1024 + (t & 3) * 8;
  const unsigned short* bg0 = W + (size_t)nt * 131072 + (size_t)(t >> 2) * 1024 + (t & 3) * 8;
  unsigned short* aw = &As[(t >> 2) * 32 + (t & 3) * 8];   // == As + t*8 (linear in t)
  unsigned short* bw = &Bs[(t >> 2) * 32 + (t & 3) * 8];   // == Bs + t*8 (linear in t)

  f32x4 acc[2][4] = {};

  for (int kt = 0; kt < 32; ++kt) {
    // issue f32 A loads before the barrier (reg-staged; no LDS hazard)
    float4 a0 = *(const float4*)(ag0 + kt * 32);
    float4 a1 = *(const float4*)(ag0 + kt * 32 + 4);
    __syncthreads();                       // prior MFMA LDS reads done
    load_lds16(bg0 + kt * 32,             bw);
    load_lds16(bg0 + kt * 32 + 64 * 1024, bw + 2048);
    union { unsigned short u[8]; uint4 v; } pa;
    pa.u[0] = f2bf(a0.x); pa.u[1] = f2bf(a0.y);
    pa.u[2] = f2bf(a0.z); pa.u[3] = f2bf(a0.w);
    pa.u[4] = f2bf(a1.x); pa.u[5] = f2bf(a1.y);
    pa.u[6] = f2bf(a1.z); pa.u[7] = f2bf(a1.w);
    *(uint4*)aw = pa.v;                    // ds_write_b128
    __syncthreads();                       // drains A ds_write + B global_load_lds

    bf16x8 af[2], bfr[4];
#pragma unroll
    for (int i = 0; i < 2; ++i)
      af[i] = *(const bf16x8*)&As[(wm * 32 + i * 16 + l15) * 32 + quad * 8];
#pragma unroll
    for (int j = 0; j < 4; ++j)
      bfr[j] = *(const bf16x8*)&Bs[(wn * 64 + j * 16 + l15) * 32 + quad * 8];
#pragma unroll
    for (int i = 0; i < 2; ++i)
#pragma unroll
      for (int j = 0; j < 4; ++j)
        acc[i][j] = mfma16(af[i], bfr[j], acc[i][j]);
  }

  if (nt != 2) {
    const int m0 = mtile * 64 + wm * 32;
#pragma unroll
    for (int i = 0; i < 2; ++i)
#pragma unroll
      for (int j = 0; j < 4; ++j)
#pragma unroll
        for (int r = 0; r < 4; ++r) {
          int m = m0 + i * 16 + quad * 4 + r;
          int n = wn * 64 + j * 16 + l15;
          float v = acc[i][j][r];
          if (nt == 0) Qb[(size_t)m * 128 + n] = f2bf(v * ATTN_SCALE);
          else         Kb[(size_t)m * 128 + n] = f2bf(v);
        }
  } else {
    // transpose through LDS -> coalesced Vt writes
    // NOTE: jj loop MUST be fully unrolled (j indexes the acc register array;
    // runtime index demotes acc to scratch -> massive spill traffic).
    float* Ts = (float*)sm;                   // [64 m][17] f32 (4352 B)
    const int bb = mtile >> 6;
    const int s0 = (mtile & 63) * 64;
#pragma unroll
    for (int jj = 0; jj < 8; ++jj) {
      __syncthreads();
      if (wn == (jj >> 2)) {
        const int j = jj & 3;
#pragma unroll
        for (int i = 0; i < 2; ++i)
#pragma unroll
          for (int r = 0; r < 4; ++r)
            Ts[(wm * 32 + i * 16 + quad * 4 + r) * 17 + l15] = acc[i][j][r];
      }
      __syncthreads();
      int n2 = jj * 16 + (t >> 4);            // d index within this 16-col chunk
      int m2 = (t & 15) * 4;                  // 4 seq rows per thread
      union { unsigned short u[4]; uint2 v; } pk;
#pragma unroll
      for (int e = 0; e < 4; ++e) pk.u[e] = f2bf(Ts[(m2 + e) * 17 + (t >> 4)]);
      *(uint2*)&Vt[((size_t)(bb * 128 + n2)) * 4096 + s0 + m2] = pk.v;
    }
  }
}

// ---------------------------------------------------------------- flash attention
// v4: occupancy bet. Rounds 2/3 proved the 54 us plateau is NOT L3 BW (FETCH
// -4.3x via XCD affinity: no change) and NOT in-block pipelining (K/V dbuf +
// counted vmcnt: no change). Issue accounting says only ~42% of cycles have
// any pipe busy at 2 waves/SIMD -> latency/occupancy gap. So: single-buffer
// K AND V, LDS 75776 -> 43008 B -> 3 blocks/CU = 12 waves/CU (+50%).
// Loop (all waits vmcnt(0); queues alternate cleanly):
//   alpha: vmcnt(0)+bar   K[t],V? resident (K issued ~1 iter ago)
//   issue V[t]            overlapped by QK+softmax (~450 cyc > L2 latency)
//   QK from K; softmax; write P
//   beta: vmcnt(0)+lgkm(0)+bar   V[t] resident + P visible; K buf free
//   issue K[t+1]          overlapped by PV + other blocks
//   PV from V + P
// Hazards: V[t] write after alpha = all PV(i-1) reads data-dep-retired;
// K[t+1] write after beta = all QK(i) reads retired; wrap-dummy K prefetch
// drained by epilogue __syncthreads before the Ob overlay (Ob covers exactly
// the dead K+V regions). Numerics bit-identical to rounds 0/2/3.
__global__ __launch_bounds__(256, 3) void k_flash(
    const unsigned short* __restrict__ Qb,   // [4][4096][128] bf16, pre-scaled
    const unsigned short* __restrict__ Kb,   // [4][4096][128] bf16
    const unsigned short* __restrict__ Vt,   // [4][128][4096] bf16
    float* __restrict__ Om,                  // [2][16384][128] f32 partials
    float* __restrict__ lp)                  // [2][16384] row sums
{
  __shared__ __align__(16) unsigned short smem[21504];   // 43008 B -> 3 blocks/CU
  // K [0,8192) | V [8192,16384) | P [16384,21504)
  unsigned short* Psh = smem + 16384;    // per-wave [32 q][stride 40]
  float* Ob  = (float*)smem;             // epilogue overlay [64][128] f32 (over K+V)
  float* lsh = (float*)(smem + 16384);   // epilogue overlay [64] f32 (over P)

  const int t = threadIdx.x;
  const int w = t >> 6, lane = t & 63, quad = lane >> 4, l15 = lane & 15;
  const int h = w & 1, p = w >> 1;
  // XCD-affine decode: xcd = bid & 7; pair (2b, 2b+1) = batch b; even XCD of
  // the pair gets keys 0..2047 (sp=0), odd 2048..4095. Keeps K/V ~1 MB/XCD L2.
  const int bid = blockIdx.x;            // 0..511
  const int b   = (bid & 7) >> 1;
  const int sp  = bid & 1;
  const int qt  = bid >> 3;              // 0..63

  const unsigned short* Qg = Qb + (size_t)(b * 4096 + qt * 64 + h * 32) * 128;
  const unsigned short* Kg = Kb + (size_t)b * 4096 * 128;
  const unsigned short* Vg = Vt + (size_t)b * 128 * 4096;

  bf16x8 qf[2][4];
#pragma unroll
  for (int mt = 0; mt < 2; ++mt)
#pragma unroll
    for (int kk = 0; kk < 4; ++kk)
      qf[mt][kk] = *(const bf16x8*)&Qg[(size_t)(mt * 16 + l15) * 128 + kk * 32 + quad * 8];

  f32x4 O[2][8] = {};
  f32x4 Ol[2] = {};

  // staging maps (chunk-XOR swizzled on the fetch side):
  // K rows are read as row = 2*l15+ntk, so swizzle granularity is (row>>1)&7.
  const unsigned short* kg0 = Kg + (size_t)(t >> 4) * 128 + (((t & 15) ^ ((t >> 5) & 7)) * 8);
  const unsigned short* vg0 = Vg + (size_t)(t >> 3) * 4096 + (((t & 7) ^ ((t >> 3) & 7)) * 8);
  unsigned short* kw = &smem[w * 512];
  unsigned short* vw = &smem[8192 + w * 512];

  const int kt0 = sp * 32;

  // prologue: K(kt0) -> K buf (V issued inside the loop after alpha)
  {
    const unsigned short* kg = kg0 + (size_t)kt0 * 8192;
#pragma unroll
    for (int it = 0; it < 4; ++it)
      load_lds16(kg + it * 2048, kw + it * 2048);
  }

  for (int i = 0; i < 32; ++i) {
    const int kt = kt0 + i;
    const int ktn = (i < 31) ? (kt + 1) : kt0;   // wrap dummy on last iter

    // alpha: K[kt] resident (own loads retired + barrier covers all waves).
    // All PV(i-1) V-reads retired (data-dep before each wave's barrier).
    asm volatile("s_waitcnt vmcnt(0)" ::: "memory");
    asm volatile("s_barrier" ::: "memory");

    // issue V[kt] -> V buf (single; safe per above). Covered by QK+softmax.
    {
      const unsigned short* vg = vg0 + (size_t)kt * 64;
#pragma unroll
      for (int it = 0; it < 4; ++it)
        load_lds16(vg + (size_t)it * 131072, vw + it * 2048);
    }

    // S = Q K^T on K buf (keys paired even/odd: lane l15 holds
    // keys p*32 + 2*l15 + ntk)
    f32x4 sc[2][2] = {};
#pragma unroll
    for (int ntk = 0; ntk < 2; ++ntk) {
      const int row = p * 32 + 2 * l15 + ntk;
#pragma unroll
      for (int kk = 0; kk < 4; ++kk) {
        bf16x8 kf = *(const bf16x8*)&smem[row * 128 + (((kk * 4 + quad) ^ (l15 & 7)) * 8)];
        sc[0][ntk] = mfma16(qf[0][kk], kf, sc[0][ntk]);
        sc[1][ntk] = mfma16(qf[1][kk], kf, sc[1][ntk]);
      }
    }

    // P = exp(S) (no max shift), packed pair writes (keys 2*l15, 2*l15+1)
#pragma unroll
    for (int mt = 0; mt < 2; ++mt)
#pragma unroll
      for (int r = 0; r < 4; ++r) {
        float e0 = __expf(sc[mt][0][r]);
        float e1 = __expf(sc[mt][1][r]);
        int row = mt * 16 + quad * 4 + r;
        uint32_t pk = (uint32_t)f2bf(e0) | ((uint32_t)f2bf(e1) << 16);
        *(uint32_t*)&Psh[w * 1280 + row * 40 + 2 * l15] = pk;
      }

    // beta: V[kt] resident (own V loads are the only outstanding vmem) +
    // own P visible; barrier -> everyone's V resident, all QK reads done.
    asm volatile("s_waitcnt vmcnt(0) lgkmcnt(0)" ::: "memory");
    asm volatile("s_barrier" ::: "memory");

    // issue K[kt+1] -> K buf (free: all QK(i) reads retired). Covered by PV.
    {
      const unsigned short* kg = kg0 + (size_t)ktn * 8192;
#pragma unroll
      for (int it = 0; it < 4; ++it)
        load_lds16(kg + it * 2048, kw + it * 2048);
    }

    bf16x8 pf0 = *(const bf16x8*)&Psh[w * 1280 + l15 * 40 + quad * 8];
    bf16x8 pf1 = *(const bf16x8*)&Psh[w * 1280 + (16 + l15) * 40 + quad * 8];
    const bf16x8 one = ones_bf16();
    Ol[0] = mfma16(pf0, one, Ol[0]);     // row-sums of P (free l accumulate)
    Ol[1] = mfma16(pf1, one, Ol[1]);
    const unsigned short* Vshc = &smem[8192];
#pragma unroll
    for (int dt = 0; dt < 8; ++dt) {
      bf16x8 vf = *(const bf16x8*)&Vshc[(dt * 16 + l15) * 64 + (((p * 4 + quad) ^ (l15 & 7)) * 8)];
      O[0][dt] = mfma16(pf0, vf, O[0][dt]);
      O[1][dt] = mfma16(pf1, vf, O[1][dt]);
    }
  }

  // ---- merge the two key-half partials (additive: no max state) ----
  // __syncthreads drains vmcnt(0) (wrap-dummy K prefetch lands BEFORE the
  // overlay writes below) + lgkmcnt, then barrier.
  __syncthreads();
  if (p == 1) {
#pragma unroll
    for (int mt = 0; mt < 2; ++mt)
#pragma unroll
      for (int r = 0; r < 4; ++r) {
        int row = h * 32 + mt * 16 + quad * 4 + r;
        if (l15 == 0) lsh[row] = Ol[mt][r];
#pragma unroll
        for (int dt = 0; dt < 8; ++dt)
          Ob[row * 128 + dt * 16 + l15] = O[mt][dt][r];
      }
  }
  __syncthreads();
  if (p == 0) {
    const size_t rowbase = (size_t)b * 4096 + qt * 64;
    float* Omp = Om + (size_t)sp * 2097152;
#pragma unroll
    for (int mt = 0; mt < 2; ++mt)
#pragma unroll
      for (int r = 0; r < 4; ++r) {
        int row = h * 32 + mt * 16 + quad * 4 + r;
#pragma unroll
        for (int dt = 0; dt < 8; ++dt)
          Omp[(rowbase + row) * 128 + dt * 16 + l15] =
              O[mt][dt][r] + Ob[row * 128 + dt * 16 + l15];
        if (l15 == 0)
          lp[(size_t)sp * 16384 + rowbase + row] = Ol[mt][r] + lsh[row];
      }
  }
}

// ---------------------------------------------------------------- merge key-splits
__global__ __launch_bounds__(256) void k_merge(const float* __restrict__ Om,
                                               const float* __restrict__ lp,
                                               float* __restrict__ out) {
  int i = blockIdx.x * 256 + threadIdx.x;   // float4 index, 524288 total
  int row = i >> 5;
  float inv = 1.0f / (lp[row] + lp[16384 + row]);
  float4 a = ((const float4*)Om)[i];
  float4 c = ((const float4*)Om)[524288 + i];
  float4 o;
  o.x = (a.x + c.x) * inv;
  o.y = (a.y + c.y) * inv;
  o.z = (a.z + c.z) * inv;
  o.w = (a.w + c.w) * inv;
  ((float4*)out)[i] = o;
}

// ---------------------------------------------------------------- launch
extern "C" void kernel_launch(void* const* d_in, const int* in_sizes, int n_in,
                              void* d_out, int out_size, void* d_ws, size_t ws_size,
                              hipStream_t stream) {
  const float* x  = (const float*)d_in[0];   // [4,4096,1024]
  const float* Wq = (const float*)d_in[1];   // [128,1024]
  const float* Wk = (const float*)d_in[2];
  const float* Wv = (const float*)d_in[3];
  float* out = (float*)d_out;                // [4,4096,128]

  unsigned short* ws  = (unsigned short*)d_ws;
  unsigned short* wbf = ws;                   // 393,216 ush
  unsigned short* Qb  = wbf + 393216;         // 2,097,152
  unsigned short* Kb  = Qb + 2097152;
  unsigned short* Vt  = Kb + 2097152;         // 2,097,152
  float* Om = (float*)(Vt + 2097152);         // 2*16384*128 f32
  float* lp = Om + 4194304;                   // 2*16384 f32

  k_cvtw<<<384, 256, 0, stream>>>(Wq, Wk, Wv, wbf);
  k_proj<<<dim3(256, 3), 256, 0, stream>>>(x, wbf, Qb, Kb, Vt);
  k_flash<<<512, 256, 0, stream>>>(Qb, Kb, Vt, Om, lp);
  k_merge<<<2048, 256, 0, stream>>>(Om, lp, out);
}